// Round 16
// baseline (133.751 us; speedup 1.0000x reference)
//
#include <hip/hip_runtime.h>
#include <stdint.h>

#define BDIM 4
#define CDIM 512
#define HDIM 128
#define WDIM 128
#define HWDIM (HDIM*WDIM)
#define SADMP 16
#define BHW 8
#define KKP 256

using short8 = __attribute__((ext_vector_type(8))) short;
using f32x4  = __attribute__((ext_vector_type(4))) float;

// manual RTN f32->bf16 — validated fastest in dist (native cvt regressed r12)
__device__ __forceinline__ unsigned short f2bf(float f) {
    unsigned u = __float_as_uint(f);
    unsigned r = (u + 0x7fffu + ((u >> 16) & 1u)) >> 16;
    return (unsigned short)r;
}
__device__ __forceinline__ float bf2f(unsigned short h) {
    return __uint_as_float(((unsigned)h) << 16);
}
__device__ __forceinline__ unsigned int ordf(float f) {
    unsigned u = __float_as_uint(f);
    return (u & 0x80000000u) ? ~u : (u | 0x80000000u);
}
// writer-side LDS drain + raw barrier; no vmcnt drain (globals stay in flight)
__device__ __forceinline__ void step_barrier() {
    asm volatile("s_waitcnt lgkmcnt(0)" ::: "memory");
    __builtin_amdgcn_s_barrier();
}

// ---------------- K1: channel-chunk partial sums (8 chunks of 64) ----------------
__global__ void resp_part_kernel(const float* __restrict__ A, float* __restrict__ part) {
    int gid = blockIdx.x * blockDim.x + threadIdx.x;   // (b*8+cq)*HW + hw
    int hw = gid & (HWDIM - 1);
    int rest = gid >> 14;
    int b = rest >> 3, cq = rest & 7;
    const float* p = A + (size_t)b * CDIM * HWDIM + (size_t)(cq * 64) * HWDIM + hw;
    float s0 = 0.f, s1 = 0.f, s2 = 0.f, s3 = 0.f;
    #pragma unroll 4
    for (int c = 0; c < 64; c += 4) {
        s0 += p[(size_t)(c + 0) * HWDIM];
        s1 += p[(size_t)(c + 1) * HWDIM];
        s2 += p[(size_t)(c + 2) * HWDIM];
        s3 += p[(size_t)(c + 3) * HWDIM];
    }
    part[gid] = (s0 + s1) + (s2 + s3);
}

// ---------------- K2: per-window argmax, comb fused (ascending cq = identical FP) ----
__global__ void argmax_kernel(const float* __restrict__ part, int* __restrict__ kp) {
    int win = blockIdx.x;                 // b*K + k
    int b = win / KKP, k = win % KKP;
    int bi = k / SADMP, bj = k % SADMP;
    int l = threadIdx.x;                  // 0..63 == loc
    int r = l >> 3, c = l & 7;
    int h = bi * BHW + r, w = bj * BHW + c;
    const float* p = part + (size_t)(b * 8) * HWDIM + h * WDIM + w;
    float v = 0.f;
    #pragma unroll
    for (int cq = 0; cq < 8; cq++) v += p[(size_t)cq * HWDIM];
    int idx = l;
    #pragma unroll
    for (int off = 32; off; off >>= 1) {
        float ov = __shfl_down(v, off);
        int   oi = __shfl_down(idx, off);
        if (ov > v || (ov == v && oi < idx)) { v = ov; idx = oi; }
    }
    if (l == 0) {
        int row = bi * BHW + (idx >> 3);
        int col = bj * BHW + (idx & 7);
        kp[win] = row * WDIM + col;
    }
}

// ---------------- K3: gather + hi/lo convert into 16x16 MFMA A-frag order + dn ----
__global__ void convert_kernel(const float* __restrict__ A, const int* __restrict__ kp,
                               uint4* __restrict__ frag, float* __restrict__ dn) {
    int blk = blockIdx.x;                 // b*16 + mf
    int b = blk >> 4, mf = blk & 15;
    int t = threadIdx.x;                  // 0..255
    int l = t & 63, q0 = t >> 6;
    int ml = l & 15;
    int m  = mf * 16 + ml;
    int cg = (l >> 4) * 8;
    int idx = kp[b * KKP + m];
    const float* Ab = A + (size_t)b * CDIM * HWDIM + idx;
    float sq = 0.f;
    #pragma unroll
    for (int qq = 0; qq < 4; qq++) {
        int q = q0 * 4 + qq;
        unsigned hi[4], lo[4];
        #pragma unroll
        for (int jj = 0; jj < 4; jj++) {
            int c0 = q * 32 + cg + jj * 2;
            float v0 = Ab[(size_t)c0 * HWDIM];
            float v1 = Ab[(size_t)(c0 + 1) * HWDIM];
            sq = fmaf(v0, v0, sq);
            sq = fmaf(v1, v1, sq);
            unsigned short h0 = f2bf(v0), h1 = f2bf(v1);
            unsigned short g0 = f2bf(v0 - bf2f(h0)), g1 = f2bf(v1 - bf2f(h1));
            hi[jj] = (unsigned)h0 | ((unsigned)h1 << 16);
            lo[jj] = (unsigned)g0 | ((unsigned)g1 << 16);
        }
        frag[((size_t)b * 2 + 0) * 16384 + mf * 1024 + q * 64 + l] = make_uint4(hi[0], hi[1], hi[2], hi[3]);
        frag[((size_t)b * 2 + 1) * 16384 + mf * 1024 + q * 64 + l] = make_uint4(lo[0], lo[1], lo[2], lo[3]);
    }
    __shared__ float red[16][17];
    red[ml][(l >> 4) * 4 + q0] = sq;
    __syncthreads();
    if (t < 16) {
        float s = 0.f;
        #pragma unroll
        for (int i = 0; i < 16; i++) s += red[t][i];
        dn[b * KKP + mf * 16 + t] = s;
    }
}

// ---------------- K4: MFMA dist + argmin (r10 base + wave phase-skew) ----------
// BM=256, BN=64, BK=64/step, 8 steps, 16x16x32, bf16 hi/lo 3-term.
// Fragment-order dbuf LDS (0 conflicts), ONE raw s_barrier/step, A-frags
// reg-dbuf'd via temps, fb 2 steps ahead, T1 batch-major swizzle, no setprio.
// NEW: wave phase-skew sk=(w>>2)&1 — same-SIMD wave pairs (w, w+4) consume
// the two ch-halves of buf[cur] in OPPOSITE order, so one wave's ds_read/VALU
// phase overlaps the other's MFMA cluster instead of lockstep-aligning.
// Both halves are valid after the barrier: order within a step is free.
__global__ __launch_bounds__(512) void dist_mfma_kernel(
    const uint4* __restrict__ fragA, const float* __restrict__ fb,
    const float* __restrict__ dn, unsigned long long* __restrict__ minkey)
{
    // T1: bijective XCD swizzle, batch-major (1024 blocks, 1024%8==0).
    const int u    = blockIdx.x;
    const int g    = (u & 7) * 128 + (u >> 3);
    const int b    = g >> 8;
    const int n0   = (g & 255) * 64;

    const int t  = threadIdx.x;
    const int l  = t & 63;
    const int w  = t >> 6;                // wave 0..7: rows w*32 .. w*32+31
    const int sk = (w >> 2) & 1;          // phase-skew: waves 0-3 ch0-first, 4-7 ch1-first

    __shared__ char sb[2][16384];         // [buf][term:2][ch:2][nf:4][1024]
    __shared__ float bnp[8][64];
    __shared__ float bnf[64];
    __shared__ float dnl[256];

    if (t < 256) dnl[t] = dn[b * KKP + t];

    f32x4 acc[2][4] = {};                 // [mfl][nf]

    const int scol = t & 63;
    const int sw   = t >> 6;
    const int wbase = ((sw >> 2) << 12) + ((scol >> 4) << 10) + (((((sw & 3) << 4) + (scol & 15))) << 4);
    const float* fbp = fb + (size_t)b * CDIM * HWDIM + (size_t)(sw * 8) * HWDIM + n0 + scol;
    float bnacc = 0.f;

    const short8* fA = (const short8*)fragA;
    const size_t a0Hi = ((size_t)b * 2 + 0) * 16384 + (size_t)(w * 2 + 0) * 1024 + l;
    const size_t a1Hi = ((size_t)b * 2 + 0) * 16384 + (size_t)(w * 2 + 1) * 1024 + l;
    const size_t a0Lo = ((size_t)b * 2 + 1) * 16384 + (size_t)(w * 2 + 0) * 1024 + l;
    const size_t a1Lo = ((size_t)b * 2 + 1) * 16384 + (size_t)(w * 2 + 1) * 1024 + l;

    float v[8];
    // prologue: step0 fb -> buf0; step1 fb loads; first-cluster frags (ch=sk); barrier.
    #pragma unroll
    for (int i = 0; i < 8; i++) v[i] = fbp[(size_t)i * HWDIM];
    {
        unsigned hi[4], lo[4];
        #pragma unroll
        for (int jj = 0; jj < 4; jj++) {
            float v0 = v[jj * 2], v1 = v[jj * 2 + 1];
            bnacc = fmaf(v0, v0, bnacc);
            bnacc = fmaf(v1, v1, bnacc);
            unsigned short h0 = f2bf(v0), h1 = f2bf(v1);
            unsigned short g0 = f2bf(v0 - bf2f(h0)), g1 = f2bf(v1 - bf2f(h1));
            hi[jj] = (unsigned)h0 | ((unsigned)h1 << 16);
            lo[jj] = (unsigned)g0 | ((unsigned)g1 << 16);
        }
        *(uint4*)(&sb[0][wbase])        = make_uint4(hi[0], hi[1], hi[2], hi[3]);
        *(uint4*)(&sb[0][wbase + 8192]) = make_uint4(lo[0], lo[1], lo[2], lo[3]);
    }
    #pragma unroll
    for (int i = 0; i < 8; i++) v[i] = fbp[(size_t)(64 + i) * HWDIM];
    // first-cluster A-frags for step 0: ch = sk
    short8 aA0 = fA[a0Hi + (size_t)sk * 64];
    short8 aA1 = fA[a1Hi + (size_t)sk * 64];
    short8 aA2 = fA[a0Lo + (size_t)sk * 64];
    short8 aA3 = fA[a1Lo + (size_t)sk * 64];
    step_barrier();

    for (int s = 0; s < 8; s++) {
        const int cur = s & 1;
        const char* rb = sb[cur];

        // staging: convert step s+1 -> buf^1; issue fb loads for s+2.
        if (s < 7) {
            unsigned hi[4], lo[4];
            #pragma unroll
            for (int jj = 0; jj < 4; jj++) {
                float v0 = v[jj * 2], v1 = v[jj * 2 + 1];
                bnacc = fmaf(v0, v0, bnacc);
                bnacc = fmaf(v1, v1, bnacc);
                unsigned short h0 = f2bf(v0), h1 = f2bf(v1);
                unsigned short g0 = f2bf(v0 - bf2f(h0)), g1 = f2bf(v1 - bf2f(h1));
                hi[jj] = (unsigned)h0 | ((unsigned)h1 << 16);
                lo[jj] = (unsigned)g0 | ((unsigned)g1 << 16);
            }
            char* wp = (char*)sb[cur ^ 1] + wbase;
            *(uint4*)(wp)        = make_uint4(hi[0], hi[1], hi[2], hi[3]);
            *(uint4*)(wp + 8192) = make_uint4(lo[0], lo[1], lo[2], lo[3]);
            if (s < 6) {
                #pragma unroll
                for (int i = 0; i < 8; i++)
                    v[i] = fbp[(size_t)((s + 2) * 64 + i) * HWDIM];
            }
        }

        // issue second-cluster A-frag loads (ch = 1-sk; land under first cluster)
        const size_t qB = (size_t)(s * 2 + (1 - sk)) * 64;
        short8 aB0 = fA[a0Hi + qB];
        short8 aB1 = fA[a1Hi + qB];
        short8 aB2 = fA[a0Lo + qB];
        short8 aB3 = fA[a1Lo + qB];

        // issue NEXT-step first-cluster loads (ch = sk) into TEMPS
        short8 aN0 = aA0, aN1 = aA1, aN2 = aA2, aN3 = aA3;
        if (s < 7) {
            const size_t qN = (size_t)(s * 2 + 2 + sk) * 64;
            aN0 = fA[a0Hi + qN];
            aN1 = fA[a1Hi + qN];
            aN2 = fA[a0Lo + qN];
            aN3 = fA[a1Lo + qN];
        }

        // two 24-MFMA clusters; skewed waves consume ch-halves in opposite order
        {
            const char* rpF = rb + sk * 4096 + l * 16;        // first cluster: ch=sk
            const char* rpS = rb + (1 - sk) * 4096 + l * 16;  // second: ch=1-sk
            #pragma unroll
            for (int nf = 0; nf < 4; nf++) {
                short8 bh = *(const short8*)(rpF + nf * 1024);
                short8 bl = *(const short8*)(rpF + nf * 1024 + 8192);
                acc[0][nf] = __builtin_amdgcn_mfma_f32_16x16x32_bf16(aA0, bh, acc[0][nf], 0, 0, 0);
                acc[0][nf] = __builtin_amdgcn_mfma_f32_16x16x32_bf16(aA0, bl, acc[0][nf], 0, 0, 0);
                acc[0][nf] = __builtin_amdgcn_mfma_f32_16x16x32_bf16(aA2, bh, acc[0][nf], 0, 0, 0);
                acc[1][nf] = __builtin_amdgcn_mfma_f32_16x16x32_bf16(aA1, bh, acc[1][nf], 0, 0, 0);
                acc[1][nf] = __builtin_amdgcn_mfma_f32_16x16x32_bf16(aA1, bl, acc[1][nf], 0, 0, 0);
                acc[1][nf] = __builtin_amdgcn_mfma_f32_16x16x32_bf16(aA3, bh, acc[1][nf], 0, 0, 0);
            }
            #pragma unroll
            for (int nf = 0; nf < 4; nf++) {
                short8 bh = *(const short8*)(rpS + nf * 1024);
                short8 bl = *(const short8*)(rpS + nf * 1024 + 8192);
                acc[0][nf] = __builtin_amdgcn_mfma_f32_16x16x32_bf16(aB0, bh, acc[0][nf], 0, 0, 0);
                acc[0][nf] = __builtin_amdgcn_mfma_f32_16x16x32_bf16(aB0, bl, acc[0][nf], 0, 0, 0);
                acc[0][nf] = __builtin_amdgcn_mfma_f32_16x16x32_bf16(aB2, bh, acc[0][nf], 0, 0, 0);
                acc[1][nf] = __builtin_amdgcn_mfma_f32_16x16x32_bf16(aB1, bh, acc[1][nf], 0, 0, 0);
                acc[1][nf] = __builtin_amdgcn_mfma_f32_16x16x32_bf16(aB1, bl, acc[1][nf], 0, 0, 0);
                acc[1][nf] = __builtin_amdgcn_mfma_f32_16x16x32_bf16(aB3, bh, acc[1][nf], 0, 0, 0);
            }
        }

        // commit A reg-dbuf for next step (loads stay in flight across barrier)
        aA0 = aN0; aA1 = aN1; aA2 = aN2; aA3 = aN3;
        if (s < 7) step_barrier();
    }

    // bn reduction
    bnp[sw][scol] = bnacc;
    __syncthreads();
    if (t < 64) {
        float s = 0.f;
        #pragma unroll
        for (int i = 0; i < 8; i++) s += bnp[i][t];
        bnf[t] = s;
    }
    __syncthreads();

    // epilogue: dist = dn - 2*cross + bn, packed argmin, atomicMin
    #pragma unroll
    for (int mfl = 0; mfl < 2; mfl++) {
        #pragma unroll
        for (int r = 0; r < 4; r++) {
            int m = w * 32 + mfl * 16 + (l >> 4) * 4 + r;
            float dnm = dnl[m];
            unsigned long long best = ~0ull;
            #pragma unroll
            for (int nf = 0; nf < 4; nf++) {
                int nloc = nf * 16 + (l & 15);
                float d = dnm - 2.f * acc[mfl][nf][r] + bnf[nloc];
                unsigned long long key = ((unsigned long long)ordf(d) << 32) | (unsigned)(n0 + nloc);
                if (key < best) best = key;
            }
            #pragma unroll
            for (int off = 1; off < 16; off <<= 1) {
                unsigned long long o = __shfl_xor(best, off);
                if (o < best) best = o;
            }
            if ((l & 15) == 0) atomicMin(&minkey[b * KKP + m], best);
        }
    }
}

// ---------------- K5: finalize ----------------
__global__ void finalize_kernel(const unsigned long long* __restrict__ minkey,
                                const int* __restrict__ kp,
                                float* __restrict__ out)
{
    int b = blockIdx.x;
    int k = threadIdx.x;
    unsigned long long key = minkey[b * KKP + k];
    unsigned n   = (unsigned)(key & 0xffffffffu);
    unsigned top = (unsigned)(key >> 32);
    unsigned fbits = (top & 0x80000000u) ? (top ^ 0x80000000u) : ~top;
    out[8 + b * KKP + k] = __uint_as_float(fbits);

    int idxA = kp[b * KKP + k];
    int rowA = idxA >> 7, colA = idxA & 127;
    int rowB = (int)(n >> 7), colB = (int)(n & 127);
    int drow = rowA - rowB, dcol = colA - colB;
    int code = (drow + 256) * 1024 + (dcol + 256);

    __shared__ int codes[KKP];
    __shared__ int keys[KKP];
    codes[k] = code;
    __syncthreads();
    int cnt = 0;
    for (int j = 0; j < KKP; j++) cnt += (codes[j] == code);
    keys[k] = cnt * 256 + (255 - k);
    __syncthreads();
    for (int s = 128; s; s >>= 1) {
        if (k < s) keys[k] = max(keys[k], keys[k + s]);
        __syncthreads();
    }
    if (k == 0) {
        int bestk = 255 - (keys[0] & 255);
        int bc = codes[bestk];
        int dr = bc / 1024 - 256, dc = bc % 1024 - 256;
        out[b * 2 + 0] = (float)dr;
        out[b * 2 + 1] = (float)dc;
    }
}

extern "C" void kernel_launch(void* const* d_in, const int* in_sizes, int n_in,
                              void* d_out, int out_size, void* d_ws, size_t ws_size,
                              hipStream_t stream) {
    const float* A  = (const float*)d_in[0];
    const float* Bf = (const float*)d_in[1];
    float* out = (float*)d_out;
    char* ws = (char*)d_ws;

    int*   kp   = (int*)(ws + 262144);                          // 4 KB
    float* dn   = (float*)(ws + 266240);                        // 4 KB
    unsigned long long* minkey = (unsigned long long*)(ws + 270336); // 8 KB
    uint4* frag = (uint4*)(ws + 278528);                        // 2 MB
    float* part = (float*)(ws + 278528 + 2097152);              // 2 MB

    hipMemsetAsync(minkey, 0xFF, BDIM * KKP * sizeof(unsigned long long), stream);
    resp_part_kernel<<<BDIM * 8 * HWDIM / 256, 256, 0, stream>>>(A, part);
    argmax_kernel<<<BDIM * KKP, 64, 0, stream>>>(part, kp);
    convert_kernel<<<BDIM * 16, 256, 0, stream>>>(A, kp, frag, dn);
    dist_mfma_kernel<<<1024, 512, 0, stream>>>(frag, Bf, dn, minkey);
    finalize_kernel<<<BDIM, KKP, 0, stream>>>(minkey, kp, out);
}

// Round 17
// 116.043 us; speedup vs baseline: 1.1526x; 1.1526x over previous
//
#include <hip/hip_runtime.h>
#include <stdint.h>

#define BDIM 4
#define CDIM 512
#define HDIM 128
#define WDIM 128
#define HWDIM (HDIM*WDIM)
#define SADMP 16
#define BHW 8
#define KKP 256

using short8 = __attribute__((ext_vector_type(8))) short;
using f32x4  = __attribute__((ext_vector_type(4))) float;

// manual RTN f32->bf16 — validated fastest in dist (native cvt regressed r12)
__device__ __forceinline__ unsigned short f2bf(float f) {
    unsigned u = __float_as_uint(f);
    unsigned r = (u + 0x7fffu + ((u >> 16) & 1u)) >> 16;
    return (unsigned short)r;
}
__device__ __forceinline__ float bf2f(unsigned short h) {
    return __uint_as_float(((unsigned)h) << 16);
}
__device__ __forceinline__ unsigned int ordf(float f) {
    unsigned u = __float_as_uint(f);
    return (u & 0x80000000u) ? ~u : (u | 0x80000000u);
}
// writer-side LDS drain + raw barrier; no vmcnt drain (globals stay in flight)
__device__ __forceinline__ void step_barrier() {
    asm volatile("s_waitcnt lgkmcnt(0)" ::: "memory");
    __builtin_amdgcn_s_barrier();
}

// ---------------- K1: channel-chunk partial sums (8 chunks of 64) ----------------
__global__ void resp_part_kernel(const float* __restrict__ A, float* __restrict__ part) {
    int gid = blockIdx.x * blockDim.x + threadIdx.x;   // (b*8+cq)*HW + hw
    int hw = gid & (HWDIM - 1);
    int rest = gid >> 14;
    int b = rest >> 3, cq = rest & 7;
    const float* p = A + (size_t)b * CDIM * HWDIM + (size_t)(cq * 64) * HWDIM + hw;
    float s0 = 0.f, s1 = 0.f, s2 = 0.f, s3 = 0.f;
    #pragma unroll 4
    for (int c = 0; c < 64; c += 4) {
        s0 += p[(size_t)(c + 0) * HWDIM];
        s1 += p[(size_t)(c + 1) * HWDIM];
        s2 += p[(size_t)(c + 2) * HWDIM];
        s3 += p[(size_t)(c + 3) * HWDIM];
    }
    part[gid] = (s0 + s1) + (s2 + s3);
}

// ---------------- K2: per-window argmax, comb fused (ascending cq = identical FP) ----
__global__ void argmax_kernel(const float* __restrict__ part, int* __restrict__ kp) {
    int win = blockIdx.x;                 // b*K + k
    int b = win / KKP, k = win % KKP;
    int bi = k / SADMP, bj = k % SADMP;
    int l = threadIdx.x;                  // 0..63 == loc
    int r = l >> 3, c = l & 7;
    int h = bi * BHW + r, w = bj * BHW + c;
    const float* p = part + (size_t)(b * 8) * HWDIM + h * WDIM + w;
    float v = 0.f;
    #pragma unroll
    for (int cq = 0; cq < 8; cq++) v += p[(size_t)cq * HWDIM];
    int idx = l;
    #pragma unroll
    for (int off = 32; off; off >>= 1) {
        float ov = __shfl_down(v, off);
        int   oi = __shfl_down(idx, off);
        if (ov > v || (ov == v && oi < idx)) { v = ov; idx = oi; }
    }
    if (l == 0) {
        int row = bi * BHW + (idx >> 3);
        int col = bj * BHW + (idx & 7);
        kp[win] = row * WDIM + col;
    }
}

// ---------------- K3: gather + hi/lo convert into 16x16 MFMA A-frag order + dn ----
__global__ void convert_kernel(const float* __restrict__ A, const int* __restrict__ kp,
                               uint4* __restrict__ frag, float* __restrict__ dn) {
    int blk = blockIdx.x;                 // b*16 + mf
    int b = blk >> 4, mf = blk & 15;
    int t = threadIdx.x;                  // 0..255
    int l = t & 63, q0 = t >> 6;
    int ml = l & 15;
    int m  = mf * 16 + ml;
    int cg = (l >> 4) * 8;
    int idx = kp[b * KKP + m];
    const float* Ab = A + (size_t)b * CDIM * HWDIM + idx;
    float sq = 0.f;
    #pragma unroll
    for (int qq = 0; qq < 4; qq++) {
        int q = q0 * 4 + qq;
        unsigned hi[4], lo[4];
        #pragma unroll
        for (int jj = 0; jj < 4; jj++) {
            int c0 = q * 32 + cg + jj * 2;
            float v0 = Ab[(size_t)c0 * HWDIM];
            float v1 = Ab[(size_t)(c0 + 1) * HWDIM];
            sq = fmaf(v0, v0, sq);
            sq = fmaf(v1, v1, sq);
            unsigned short h0 = f2bf(v0), h1 = f2bf(v1);
            unsigned short g0 = f2bf(v0 - bf2f(h0)), g1 = f2bf(v1 - bf2f(h1));
            hi[jj] = (unsigned)h0 | ((unsigned)h1 << 16);
            lo[jj] = (unsigned)g0 | ((unsigned)g1 << 16);
        }
        frag[((size_t)b * 2 + 0) * 16384 + mf * 1024 + q * 64 + l] = make_uint4(hi[0], hi[1], hi[2], hi[3]);
        frag[((size_t)b * 2 + 1) * 16384 + mf * 1024 + q * 64 + l] = make_uint4(lo[0], lo[1], lo[2], lo[3]);
    }
    __shared__ float red[16][17];
    red[ml][(l >> 4) * 4 + q0] = sq;
    __syncthreads();
    if (t < 16) {
        float s = 0.f;
        #pragma unroll
        for (int i = 0; i < 16; i++) s += red[t][i];
        dn[b * KKP + mf * 16 + t] = s;
    }
}

// ---------------- K4: MFMA dist + argmin (r10/r15 structure — validated best) ------
// BM=256, BN=64, BK=64/step, 8 steps, 16x16x32, bf16 hi/lo 3-term.
// Fragment-order dbuf LDS (0 conflicts), ONE raw s_barrier/step.
// A-frags register-double-buffered via temps (aN*), committed after the
// merged 48-MFMA cluster; fb 2 steps ahead; T1 batch-major swizzle.
// No setprio (r15 A/B: null, m190 confirmed); no phase-skew (r16: VGPR 72,
// occupancy cliff, regressed).
__global__ __launch_bounds__(512) void dist_mfma_kernel(
    const uint4* __restrict__ fragA, const float* __restrict__ fb,
    const float* __restrict__ dn, unsigned long long* __restrict__ minkey)
{
    // T1: bijective XCD swizzle, batch-major (1024 blocks, 1024%8==0).
    const int u    = blockIdx.x;
    const int g    = (u & 7) * 128 + (u >> 3);
    const int b    = g >> 8;
    const int n0   = (g & 255) * 64;

    const int t  = threadIdx.x;
    const int l  = t & 63;
    const int w  = t >> 6;                // wave 0..7: rows w*32 .. w*32+31

    __shared__ char sb[2][16384];         // [buf][term:2][ch:2][nf:4][1024]
    __shared__ float bnp[8][64];
    __shared__ float bnf[64];
    __shared__ float dnl[256];

    if (t < 256) dnl[t] = dn[b * KKP + t];

    f32x4 acc[2][4] = {};                 // [mfl][nf]

    const int scol = t & 63;
    const int sw   = t >> 6;
    const int wbase = ((sw >> 2) << 12) + ((scol >> 4) << 10) + (((((sw & 3) << 4) + (scol & 15))) << 4);
    const float* fbp = fb + (size_t)b * CDIM * HWDIM + (size_t)(sw * 8) * HWDIM + n0 + scol;
    float bnacc = 0.f;

    const short8* fA = (const short8*)fragA;
    const size_t a0Hi = ((size_t)b * 2 + 0) * 16384 + (size_t)(w * 2 + 0) * 1024 + l;
    const size_t a1Hi = ((size_t)b * 2 + 0) * 16384 + (size_t)(w * 2 + 1) * 1024 + l;
    const size_t a0Lo = ((size_t)b * 2 + 1) * 16384 + (size_t)(w * 2 + 0) * 1024 + l;
    const size_t a1Lo = ((size_t)b * 2 + 1) * 16384 + (size_t)(w * 2 + 1) * 1024 + l;

    float v[8];
    // prologue: step0 fb -> buf0; step1 fb loads; step0 ch0 frags; barrier.
    #pragma unroll
    for (int i = 0; i < 8; i++) v[i] = fbp[(size_t)i * HWDIM];
    {
        unsigned hi[4], lo[4];
        #pragma unroll
        for (int jj = 0; jj < 4; jj++) {
            float v0 = v[jj * 2], v1 = v[jj * 2 + 1];
            bnacc = fmaf(v0, v0, bnacc);
            bnacc = fmaf(v1, v1, bnacc);
            unsigned short h0 = f2bf(v0), h1 = f2bf(v1);
            unsigned short g0 = f2bf(v0 - bf2f(h0)), g1 = f2bf(v1 - bf2f(h1));
            hi[jj] = (unsigned)h0 | ((unsigned)h1 << 16);
            lo[jj] = (unsigned)g0 | ((unsigned)g1 << 16);
        }
        *(uint4*)(&sb[0][wbase])        = make_uint4(hi[0], hi[1], hi[2], hi[3]);
        *(uint4*)(&sb[0][wbase + 8192]) = make_uint4(lo[0], lo[1], lo[2], lo[3]);
    }
    #pragma unroll
    for (int i = 0; i < 8; i++) v[i] = fbp[(size_t)(64 + i) * HWDIM];
    short8 aA0 = fA[a0Hi], aA1 = fA[a1Hi], aA2 = fA[a0Lo], aA3 = fA[a1Lo];
    step_barrier();

    for (int s = 0; s < 8; s++) {
        const int cur = s & 1;
        const char* rb = sb[cur];

        // staging: convert step s+1 -> buf^1; issue fb loads for s+2.
        if (s < 7) {
            unsigned hi[4], lo[4];
            #pragma unroll
            for (int jj = 0; jj < 4; jj++) {
                float v0 = v[jj * 2], v1 = v[jj * 2 + 1];
                bnacc = fmaf(v0, v0, bnacc);
                bnacc = fmaf(v1, v1, bnacc);
                unsigned short h0 = f2bf(v0), h1 = f2bf(v1);
                unsigned short g0 = f2bf(v0 - bf2f(h0)), g1 = f2bf(v1 - bf2f(h1));
                hi[jj] = (unsigned)h0 | ((unsigned)h1 << 16);
                lo[jj] = (unsigned)g0 | ((unsigned)g1 << 16);
            }
            char* wp = (char*)sb[cur ^ 1] + wbase;
            *(uint4*)(wp)        = make_uint4(hi[0], hi[1], hi[2], hi[3]);
            *(uint4*)(wp + 8192) = make_uint4(lo[0], lo[1], lo[2], lo[3]);
            if (s < 6) {
                #pragma unroll
                for (int i = 0; i < 8; i++)
                    v[i] = fbp[(size_t)((s + 2) * 64 + i) * HWDIM];
            }
        }

        // issue ch1 A-frag loads (land under the first 24 MFMAs)
        const size_t qB = (size_t)(s * 2 + 1) * 64;
        short8 aB0 = fA[a0Hi + qB];
        short8 aB1 = fA[a1Hi + qB];
        short8 aB2 = fA[a0Lo + qB];
        short8 aB3 = fA[a1Lo + qB];

        // issue NEXT-step ch0 A-frag loads into TEMPS (aA* still live below)
        short8 aN0 = aA0, aN1 = aA1, aN2 = aA2, aN3 = aA3;
        if (s < 7) {
            const size_t qN = (size_t)(s * 2 + 2) * 64;
            aN0 = fA[a0Hi + qN];
            aN1 = fA[a1Hi + qN];
            aN2 = fA[a0Lo + qN];
            aN3 = fA[a1Lo + qN];
        }

        // merged 48-MFMA cluster
        {
            const char* rp0 = rb + l * 16;
            const char* rp1 = rb + 4096 + l * 16;
            #pragma unroll
            for (int nf = 0; nf < 4; nf++) {
                short8 bh = *(const short8*)(rp0 + nf * 1024);
                short8 bl = *(const short8*)(rp0 + nf * 1024 + 8192);
                acc[0][nf] = __builtin_amdgcn_mfma_f32_16x16x32_bf16(aA0, bh, acc[0][nf], 0, 0, 0);
                acc[0][nf] = __builtin_amdgcn_mfma_f32_16x16x32_bf16(aA0, bl, acc[0][nf], 0, 0, 0);
                acc[0][nf] = __builtin_amdgcn_mfma_f32_16x16x32_bf16(aA2, bh, acc[0][nf], 0, 0, 0);
                acc[1][nf] = __builtin_amdgcn_mfma_f32_16x16x32_bf16(aA1, bh, acc[1][nf], 0, 0, 0);
                acc[1][nf] = __builtin_amdgcn_mfma_f32_16x16x32_bf16(aA1, bl, acc[1][nf], 0, 0, 0);
                acc[1][nf] = __builtin_amdgcn_mfma_f32_16x16x32_bf16(aA3, bh, acc[1][nf], 0, 0, 0);
            }
            #pragma unroll
            for (int nf = 0; nf < 4; nf++) {
                short8 bh = *(const short8*)(rp1 + nf * 1024);
                short8 bl = *(const short8*)(rp1 + nf * 1024 + 8192);
                acc[0][nf] = __builtin_amdgcn_mfma_f32_16x16x32_bf16(aB0, bh, acc[0][nf], 0, 0, 0);
                acc[0][nf] = __builtin_amdgcn_mfma_f32_16x16x32_bf16(aB0, bl, acc[0][nf], 0, 0, 0);
                acc[0][nf] = __builtin_amdgcn_mfma_f32_16x16x32_bf16(aB2, bh, acc[0][nf], 0, 0, 0);
                acc[1][nf] = __builtin_amdgcn_mfma_f32_16x16x32_bf16(aB1, bh, acc[1][nf], 0, 0, 0);
                acc[1][nf] = __builtin_amdgcn_mfma_f32_16x16x32_bf16(aB1, bl, acc[1][nf], 0, 0, 0);
                acc[1][nf] = __builtin_amdgcn_mfma_f32_16x16x32_bf16(aB3, bh, acc[1][nf], 0, 0, 0);
            }
        }

        // commit A reg-dbuf for next step (loads stay in flight across barrier)
        aA0 = aN0; aA1 = aN1; aA2 = aN2; aA3 = aN3;
        if (s < 7) step_barrier();
    }

    // bn reduction
    bnp[sw][scol] = bnacc;
    __syncthreads();
    if (t < 64) {
        float s = 0.f;
        #pragma unroll
        for (int i = 0; i < 8; i++) s += bnp[i][t];
        bnf[t] = s;
    }
    __syncthreads();

    // epilogue: dist = dn - 2*cross + bn, packed argmin, atomicMin
    #pragma unroll
    for (int mfl = 0; mfl < 2; mfl++) {
        #pragma unroll
        for (int r = 0; r < 4; r++) {
            int m = w * 32 + mfl * 16 + (l >> 4) * 4 + r;
            float dnm = dnl[m];
            unsigned long long best = ~0ull;
            #pragma unroll
            for (int nf = 0; nf < 4; nf++) {
                int nloc = nf * 16 + (l & 15);
                float d = dnm - 2.f * acc[mfl][nf][r] + bnf[nloc];
                unsigned long long key = ((unsigned long long)ordf(d) << 32) | (unsigned)(n0 + nloc);
                if (key < best) best = key;
            }
            #pragma unroll
            for (int off = 1; off < 16; off <<= 1) {
                unsigned long long o = __shfl_xor(best, off);
                if (o < best) best = o;
            }
            if ((l & 15) == 0) atomicMin(&minkey[b * KKP + m], best);
        }
    }
}

// ---------------- K5: finalize ----------------
__global__ void finalize_kernel(const unsigned long long* __restrict__ minkey,
                                const int* __restrict__ kp,
                                float* __restrict__ out)
{
    int b = blockIdx.x;
    int k = threadIdx.x;
    unsigned long long key = minkey[b * KKP + k];
    unsigned n   = (unsigned)(key & 0xffffffffu);
    unsigned top = (unsigned)(key >> 32);
    unsigned fbits = (top & 0x80000000u) ? (top ^ 0x80000000u) : ~top;
    out[8 + b * KKP + k] = __uint_as_float(fbits);

    int idxA = kp[b * KKP + k];
    int rowA = idxA >> 7, colA = idxA & 127;
    int rowB = (int)(n >> 7), colB = (int)(n & 127);
    int drow = rowA - rowB, dcol = colA - colB;
    int code = (drow + 256) * 1024 + (dcol + 256);

    __shared__ int codes[KKP];
    __shared__ int keys[KKP];
    codes[k] = code;
    __syncthreads();
    int cnt = 0;
    for (int j = 0; j < KKP; j++) cnt += (codes[j] == code);
    keys[k] = cnt * 256 + (255 - k);
    __syncthreads();
    for (int s = 128; s; s >>= 1) {
        if (k < s) keys[k] = max(keys[k], keys[k + s]);
        __syncthreads();
    }
    if (k == 0) {
        int bestk = 255 - (keys[0] & 255);
        int bc = codes[bestk];
        int dr = bc / 1024 - 256, dc = bc % 1024 - 256;
        out[b * 2 + 0] = (float)dr;
        out[b * 2 + 1] = (float)dc;
    }
}

extern "C" void kernel_launch(void* const* d_in, const int* in_sizes, int n_in,
                              void* d_out, int out_size, void* d_ws, size_t ws_size,
                              hipStream_t stream) {
    const float* A  = (const float*)d_in[0];
    const float* Bf = (const float*)d_in[1];
    float* out = (float*)d_out;
    char* ws = (char*)d_ws;

    int*   kp   = (int*)(ws + 262144);                          // 4 KB
    float* dn   = (float*)(ws + 266240);                        // 4 KB
    unsigned long long* minkey = (unsigned long long*)(ws + 270336); // 8 KB
    uint4* frag = (uint4*)(ws + 278528);                        // 2 MB
    float* part = (float*)(ws + 278528 + 2097152);              // 2 MB

    hipMemsetAsync(minkey, 0xFF, BDIM * KKP * sizeof(unsigned long long), stream);
    resp_part_kernel<<<BDIM * 8 * HWDIM / 256, 256, 0, stream>>>(A, part);
    argmax_kernel<<<BDIM * KKP, 64, 0, stream>>>(part, kp);
    convert_kernel<<<BDIM * 16, 256, 0, stream>>>(A, kp, frag, dn);
    dist_mfma_kernel<<<1024, 512, 0, stream>>>(frag, Bf, dn, minkey);
    finalize_kernel<<<BDIM, KKP, 0, stream>>>(minkey, kp, out);
}